// Round 15
// baseline (227.446 us; speedup 1.0000x reference)
//
#include <hip/hip_runtime.h>
#include <hip/hip_bf16.h>

#define BN_EPS 1e-5f
constexpr int C = 256;

typedef __attribute__((ext_vector_type(8))) short bf16x8;
typedef __attribute__((ext_vector_type(4))) float f32x4;

static __device__ __forceinline__ unsigned short f2bf(float f) {
    __hip_bfloat16 h = __float2bfloat16(f);
    return *reinterpret_cast<unsigned short*>(&h);
}
static __device__ __forceinline__ float bf2f(unsigned short u) {
    unsigned int v = ((unsigned int)u) << 16;
    return __uint_as_float(v);
}
static __device__ __forceinline__ unsigned int pack_bf2(float a, float b) {
    return (unsigned int)f2bf(a) | ((unsigned int)f2bf(b) << 16);
}

// ---------------------------------------------------------------------------
// WPREP: fold BN scale into weights, transpose [N][C][9] f32 -> [9][N][C] bf16.
// ---------------------------------------------------------------------------
__global__ __launch_bounds__(256) void wprep_both(
    const float* __restrict__ wk, const float* __restrict__ bkg, const float* __restrict__ bkv,
    unsigned short* __restrict__ wkt,
    const float* __restrict__ ws, const float* __restrict__ bsg, const float* __restrict__ bsv,
    unsigned short* __restrict__ wst)
{
    const int bid = blockIdx.x, t = threadIdx.x;
    const bool isk = bid < 256;
    const int n = isk ? bid : bid - 256;
    const float* w = isk ? wk : ws;
    const float* g = isk ? bkg : bsg;
    const float* v = isk ? bkv : bsv;
    unsigned short* wt = isk ? wkt : wst;
    const float scale = g[n] * rsqrtf(v[n] + BN_EPS);
    const float* wp = w + ((size_t)n * C + t) * 9;
#pragma unroll
    for (int k = 0; k < 9; ++k)
        wt[((size_t)k * C + n) * C + t] = f2bf(wp[k] * scale);
}

// ---------------------------------------------------------------------------
// MEGA (persistent, perfectly packed): grid = 256 blocks, 1 block/CU.
// Each block: 2 search-conv tiles (ids bid, bid+256) + 1 kernel-conv unit
// (id bid: 64 batch-pairs x 4 N-quarters). Zero scheduling tail.
// ---------------------------------------------------------------------------
__global__ __launch_bounds__(512, 2) void mega_conv(
    const float* __restrict__ sin_,          // [128][256][961] fp32
    const float* __restrict__ kin,           // [128][256][49]  fp32
    const unsigned short* __restrict__ wst,  // [9][256][256] bf16
    const unsigned short* __restrict__ wkt,  // [9][256][256] bf16
    const float* __restrict__ bsg, const float* __restrict__ bsb,
    const float* __restrict__ bsm, const float* __restrict__ bsv,
    const float* __restrict__ bkg, const float* __restrict__ bkb,
    const float* __restrict__ bkm, const float* __restrict__ bkv,
    unsigned short* __restrict__ sbuf,       // [128][256][844] bf16
    float* __restrict__ kbuf)                // [128][256][28]  f32
{
    constexpr int WOUT = 29, NPOS = 841;
    constexpr int BM = 224, MF = 7, NF = 4;
    constexpr int LDK = 36;
    constexpr int ROWS = 11;
    constexpr int APIX = ROWS * 31;          // 341
    constexpr int ABUF = APIX * LDK;         // 12276 shorts
    constexpr int BBUF = 256 * LDK;          // 9216 shorts
    constexpr int BIT = 2;

    __shared__ __align__(16) short s_a[2 * ABUF];   // 49,104 B
    __shared__ __align__(16) short s_b[4 * BBUF];   // 73,728 B

    const int t = threadIdx.x;
    const int lane = t & 63, wave = t >> 6;
    const int lr = lane >> 4, lc = lane & 15;
    const int wm = wave >> 2, wn = wave & 3;

    // =====================================================================
    // Part 1: two search-conv tiles
    // =====================================================================
#pragma unroll 1
    for (int sit = 0; sit < 2; ++sit) {
        const int sid = blockIdx.x + sit * 256;
        const int p0 = (sid & 3) * BM;
        const int b  = sid >> 2;
        const int y0 = p0 / WOUT;
        const int R  = min(ROWS, 31 - y0);
        const int npix = R * 31;

        int arow[MF];
#pragma unroll
        for (int m = 0; m < MF; ++m) {
            int pm = wm * 112 + m * 16 + lc;
            int p = p0 + pm; p = p < NPOS ? p : NPOS - 1;
            int y = p / WOUT, x = p - y * WOUT;
            arow[m] = ((y - y0) * 31 + x) * LDK + lr * 8;
        }

        const float* abase = sin_ + (size_t)b * C * 961 + y0 * 31 + lane;
        bool segv[6];
        int dstq[2];
#pragma unroll
        for (int seg = 0; seg < 6; ++seg) segv[seg] = (seg * 64 + lane) < npix;
#pragma unroll
        for (int q = 0; q < 2; ++q) dstq[q] = 2 * (wave + q * 8);

        float a0s[12], a1s[12];
#define SA_LOAD(c0_)                                                           \
        _Pragma("unroll")                                                      \
        for (int q = 0; q < 2; ++q) {                                          \
            const size_t cq_ = (size_t)((c0_) + dstq[q]) * 961;                \
            _Pragma("unroll")                                                  \
            for (int seg = 0; seg < 6; ++seg) {                                \
                if (segv[seg]) {                                               \
                    a0s[q * 6 + seg] = abase[cq_ + seg * 64];                  \
                    a1s[q * 6 + seg] = abase[cq_ + 961 + seg * 64];            \
                }                                                              \
            }                                                                  \
        }
#define SA_WRITE(dst_)                                                         \
        _Pragma("unroll")                                                      \
        for (int q = 0; q < 2; ++q) {                                          \
            _Pragma("unroll")                                                  \
            for (int seg = 0; seg < 6; ++seg) {                                \
                if (segv[seg])                                                 \
                    *(unsigned int*)&s_a[(dst_) + (seg * 64 + lane) * LDK + dstq[q]] = \
                        pack_bf2(a0s[q * 6 + seg], a1s[q * 6 + seg]);          \
            }                                                                  \
        }

        const unsigned short* bptr[BIT]; int boff[BIT];
#pragma unroll
        for (int it = 0; it < BIT; ++it) {
            int i = t + it * 512;
            int n = i >> 2, sl = i & 3;
            bptr[it] = wst + (size_t)n * 256 + sl * 8;
            boff[it] = n * LDK + sl * 8;
        }

        f32x4 acc[MF][NF];
#pragma unroll
        for (int m = 0; m < MF; ++m)
#pragma unroll
            for (int n = 0; n < NF; ++n) acc[m][n] = f32x4{0.f, 0.f, 0.f, 0.f};

        bf16x8 bstg0[BIT], bstg1[BIT];

        SA_LOAD(0)
#pragma unroll
        for (int it = 0; it < BIT; ++it) bstg0[it] = *(const bf16x8*)(bptr[it]);
#pragma unroll
        for (int it = 0; it < BIT; ++it) bstg1[it] = *(const bf16x8*)(bptr[it] + 65536);
        SA_WRITE(0)
#pragma unroll
        for (int it = 0; it < BIT; ++it) *(bf16x8*)&s_b[boff[it]] = bstg0[it];
#pragma unroll
        for (int it = 0; it < BIT; ++it) *(bf16x8*)&s_b[BBUF + boff[it]] = bstg1[it];
        __syncthreads();

#define READ_FRAGS(S, AF, BF)                                                  \
        {                                                                      \
            const int tap_ = (S) % 9;                                          \
            const int dt_ = (tap_ / 3) * 31 + (tap_ % 3);                      \
            const int ab_ = (((S) / 9) & 1) * ABUF;                            \
            const int bb_ = ((S) & 3) * BBUF;                                  \
            _Pragma("unroll")                                                  \
            for (int n = 0; n < NF; ++n)                                       \
                BF[n] = *(const bf16x8*)&s_b[bb_ + (wn * 64 + n * 16 + lc) * LDK + lr * 8]; \
            _Pragma("unroll")                                                  \
            for (int m = 0; m < MF; ++m)                                       \
                AF[m] = *(const bf16x8*)&s_a[ab_ + arow[m] + dt_ * LDK];       \
        }

#define MFMA_STEP(AF, BF)                                                      \
        _Pragma("unroll")                                                      \
        for (int m = 0; m < MF; ++m)                                           \
            _Pragma("unroll")                                                  \
            for (int n = 0; n < NF; ++n)                                       \
                acc[m][n] = __builtin_amdgcn_mfma_f32_16x16x32_bf16(           \
                    AF[m], BF[n], acc[m][n], 0, 0, 0);

#pragma unroll 1
        for (int pr = 0; pr < 35; ++pr) {
            const int s0 = 2 * pr, s1 = s0 + 1;

            {
                const int cb = (s0 % 9 == 0) ? s0 / 9 : ((s1 % 9 == 0) ? s1 / 9 : -1);
                if (cb >= 0 && cb < 7) {
                    const int cn = (cb + 1) * 32;
                    SA_LOAD(cn)
                }
            }

            bf16x8 af0[MF], bf0[NF], af1[MF], bf1[NF];
            READ_FRAGS(s0, af0, bf0)
            READ_FRAGS(s1, af1, bf1)

            MFMA_STEP(af0, bf0)

            {
                const int u0 = s0 + 2, u1 = s1 + 2;
                const int t0 = u0 % 9, c0_ = (u0 / 9) * 32;
                const int t1 = u1 % 9, c1_ = (u1 / 9) * 32;
#pragma unroll
                for (int it = 0; it < BIT; ++it)
                    bstg0[it] = *(const bf16x8*)(bptr[it] + (size_t)t0 * 65536 + c0_);
#pragma unroll
                for (int it = 0; it < BIT; ++it)
                    bstg1[it] = *(const bf16x8*)(bptr[it] + (size_t)t1 * 65536 + c1_);
            }

            MFMA_STEP(af1, bf1)

            {
                const int w0 = ((s0 + 2) & 3) * BBUF, w1 = ((s1 + 2) & 3) * BBUF;
#pragma unroll
                for (int it = 0; it < BIT; ++it)
                    *(bf16x8*)&s_b[w0 + boff[it]] = bstg0[it];
#pragma unroll
                for (int it = 0; it < BIT; ++it)
                    *(bf16x8*)&s_b[w1 + boff[it]] = bstg1[it];
            }

            {
                const int cw = (s0 % 9 == 7) ? s0 / 9 : ((s1 % 9 == 7) ? s1 / 9 : -1);
                if (cw >= 0 && cw < 7) {
                    const int dst = ((cw & 1) ^ 1) * ABUF;
                    SA_WRITE(dst)
                }
            }
            __syncthreads();
        }

        {
            bf16x8 af0[MF], bf0[NF], af1[MF], bf1[NF];
            READ_FRAGS(70, af0, bf0)
            READ_FRAGS(71, af1, bf1)
            MFMA_STEP(af0, bf0)
            MFMA_STEP(af1, bf1)
        }

        // epilogue: bias + relu -> bf16 planes (padded stride 844)
#pragma unroll
        for (int n = 0; n < NF; ++n) {
            const int co = wn * 64 + n * 16 + lc;
            const float sc = bsg[co] * rsqrtf(bsv[co] + BN_EPS);
            const float bias = bsb[co] - bsm[co] * sc;
#pragma unroll
            for (int m = 0; m < MF; ++m) {
                int pm = wm * 112 + m * 16 + lr * 4;
                int p = p0 + pm;
                f32x4 v = acc[m][n];
                float r0 = fmaxf(v.x + bias, 0.f);
                float r1 = fmaxf(v.y + bias, 0.f);
                float r2 = fmaxf(v.z + bias, 0.f);
                float r3 = fmaxf(v.w + bias, 0.f);
                unsigned short* op = sbuf + ((size_t)b * C + co) * 844 + p;
                if (p + 4 <= NPOS) {
                    ushort4 pk;
                    pk.x = f2bf(r0); pk.y = f2bf(r1); pk.z = f2bf(r2); pk.w = f2bf(r3);
                    *(ushort4*)op = pk;
                } else {
                    float rr[4] = {r0, r1, r2, r3};
#pragma unroll
                    for (int i = 0; i < 4; ++i)
                        if (p + i < NPOS) op[i] = f2bf(rr[i]);
                }
            }
        }
        __syncthreads();   // LDS reused by next item
#undef READ_FRAGS
#undef MFMA_STEP
#undef SA_LOAD
#undef SA_WRITE
    }

    // =====================================================================
    // Part 2: one kernel-conv unit (kb = bid): 2 batches x 64 outch.
    // =====================================================================
    {
        constexpr int KW = 7, KHW = 49, KWOUT = 5, KNPOS = 25;
        constexpr int KMF = 2;
        const int kb = blockIdx.x;           // 0..255
        const int n0 = (kb & 3) * 64;
        const int b0 = (kb >> 2) * 2;

        short* ka = s_a;                      // [2*49][36] shorts

        int arow[KMF];
#pragma unroll
        for (int m = 0; m < KMF; ++m) {
            int p = m * 16 + lc;
            p = p < KNPOS ? p : KNPOS - 1;
            int y = p / KWOUT, x = p - y * KWOUT;
            arow[m] = ((wm * KHW) + y * KW + x) * LDK + lr * 8;
        }

        f32x4 acc[KMF];
#pragma unroll
        for (int m = 0; m < KMF; ++m) acc[m] = f32x4{0.f, 0.f, 0.f, 0.f};

        const bool kval = lane < KHW;
        int sbb[4], scq[4];
#pragma unroll
        for (int j = 0; j < 4; ++j) {
            int idx = wave * 4 + j;
            sbb[j] = idx >> 4; scq[j] = (idx & 15) * 2;
        }
        const float* kbase = kin + (size_t)b0 * C * KHW + lane;

        float k0s[4], k1s[4];
#define KA_LOAD(c0_)                                                           \
        _Pragma("unroll")                                                      \
        for (int j = 0; j < 4; ++j) {                                          \
            if (kval) {                                                        \
                const float* p_ = kbase + ((size_t)sbb[j] * C + (c0_) + scq[j]) * KHW; \
                k0s[j] = p_[0]; k1s[j] = p_[KHW];                              \
            }                                                                  \
        }
#define KA_WRITE()                                                             \
        _Pragma("unroll")                                                      \
        for (int j = 0; j < 4; ++j) {                                          \
            if (kval)                                                          \
                *(unsigned int*)&ka[(sbb[j] * KHW + lane) * LDK + scq[j]] =    \
                    pack_bf2(k0s[j], k1s[j]);                                  \
        }

        const unsigned short* wb = wkt + (size_t)(n0 + wn * 16 + lc) * C + lr * 8;

        KA_LOAD(0)
        KA_WRITE()

#pragma unroll 1
        for (int ch = 0; ch < 8; ++ch) {
            const int c0 = ch * 32;
            __syncthreads();

            if (ch < 7) { KA_LOAD(c0 + 32) }

            bf16x8 bcur, bnxt;
            bnxt = *(const bf16x8*)&wb[c0];

#pragma unroll
            for (int tap = 0; tap < 9; ++tap) {
                const int dy = tap / 3, dx = tap % 3;
                bcur = bnxt;
                if (tap < 8)
                    bnxt = *(const bf16x8*)&wb[(size_t)(tap + 1) * (C * C) + c0];
                bf16x8 af[KMF];
#pragma unroll
                for (int m = 0; m < KMF; ++m)
                    af[m] = *(const bf16x8*)&ka[arow[m] + (dy * KW + dx) * LDK];
#pragma unroll
                for (int m = 0; m < KMF; ++m)
                    acc[m] = __builtin_amdgcn_mfma_f32_16x16x32_bf16(
                        af[m], bcur, acc[m], 0, 0, 0);
            }

            __syncthreads();
            if (ch < 7) { KA_WRITE() }
        }
#undef KA_LOAD
#undef KA_WRITE

        {
            const int co = n0 + wn * 16 + lc;
            const float sc = bkg[co] * rsqrtf(bkv[co] + BN_EPS);
            const float bias = bkb[co] - bkm[co] * sc;
#pragma unroll
            for (int m = 0; m < KMF; ++m) {
                int p = m * 16 + lr * 4;
                int b = b0 + wm;
                f32x4 v = acc[m];
                float rr[4] = {fmaxf(v.x + bias, 0.f), fmaxf(v.y + bias, 0.f),
                               fmaxf(v.z + bias, 0.f), fmaxf(v.w + bias, 0.f)};
                float* op = kbuf + ((size_t)b * C + co) * 28 + p;
#pragma unroll
                for (int i = 0; i < 4; ++i)
                    if (p + i < KNPOS) op[i] = rr[i];
            }
        }
    }
}

// ---------------------------------------------------------------------------
// Depthwise 5x5 valid xcorr: 2 channels/block, 5 outputs/thread (5x9 window).
// ---------------------------------------------------------------------------
__global__ __launch_bounds__(256) void xcorr_dw(
    const unsigned short* __restrict__ s, const float* __restrict__ k,
    float* __restrict__ out)
{
    const int bc0 = blockIdx.x * 2;
    const int t = threadIdx.x;

    __shared__ float s_s[2][844];
    __shared__ float s_k[2][25];

#pragma unroll
    for (int it = 0; it < 2; ++it) {
        int i = t + it * 256;
        if (i < 422) {
            int pl = i < 211 ? 0 : 1;
            int q = i - pl * 211;
            ushort4 v = *(const ushort4*)(s + (size_t)(bc0 + pl) * 844 + 4 * q);
            s_s[pl][4 * q + 0] = bf2f(v.x);
            s_s[pl][4 * q + 1] = bf2f(v.y);
            s_s[pl][4 * q + 2] = bf2f(v.z);
            s_s[pl][4 * q + 3] = bf2f(v.w);
        }
    }
    if (t < 50) s_k[t / 25][t % 25] = k[(size_t)(bc0 + t / 25) * 28 + t % 25];
    __syncthreads();

    if (t >= 250) return;
    const int ch = t / 125;
    const int r = t - ch * 125;
    const int y = r / 5;
    const int xb = (r - y * 5) * 5;

    float kk[25];
#pragma unroll
    for (int i = 0; i < 25; ++i) kk[i] = s_k[ch][i];

    float w[5][9];
#pragma unroll
    for (int dy = 0; dy < 5; ++dy)
#pragma unroll
        for (int dx = 0; dx < 9; ++dx)
            w[dy][dx] = s_s[ch][(y + dy) * 29 + xb + dx];

    float o[5] = {0.f, 0.f, 0.f, 0.f, 0.f};
#pragma unroll
    for (int dy = 0; dy < 5; ++dy)
#pragma unroll
        for (int dx = 0; dx < 5; ++dx) {
            const float kv = kk[dy * 5 + dx];
#pragma unroll
            for (int oo = 0; oo < 5; ++oo)
                o[oo] += w[dy][oo + dx] * kv;
        }

    float* op = out + (size_t)(bc0 + ch) * 625 + y * 25 + xb;
#pragma unroll
    for (int oo = 0; oo < 5; ++oo) op[oo] = o[oo];
}

extern "C" void kernel_launch(void* const* d_in, const int* in_sizes, int n_in,
                              void* d_out, int out_size, void* d_ws, size_t ws_size,
                              hipStream_t stream) {
    const float* kin = (const float*)d_in[0];   // [128,256,7,7]
    const float* sin_ = (const float*)d_in[1];  // [128,256,31,31]
    const float* wk = (const float*)d_in[2];
    const float* bkg = (const float*)d_in[3];
    const float* bkb = (const float*)d_in[4];
    const float* bkm = (const float*)d_in[5];
    const float* bkv = (const float*)d_in[6];
    const float* ws_ = (const float*)d_in[7];
    const float* bsg = (const float*)d_in[8];
    const float* bsb = (const float*)d_in[9];
    const float* bsm = (const float*)d_in[10];
    const float* bsv = (const float*)d_in[11];
    float* out = (float*)d_out;

    // workspace: wkt | wst | sbuf bf16 [128][256][844] | kbuf f32 [128][256][28]
    char* base = (char*)d_ws;
    unsigned short* wkt = (unsigned short*)base;               // 1,179,648 B
    unsigned short* wst = wkt + (size_t)9 * C * C;             // 1,179,648 B
    unsigned short* sbuf = (unsigned short*)(base + 2359296);  // 55,312,384 B
    float* kbuf = (float*)(base + 2359296 + 55312384);         //  3,670,016 B

    // L1: weight prep (both convs)
    wprep_both<<<512, 256, 0, stream>>>(wk, bkg, bkv, wkt, ws_, bsg, bsv, wst);

    // L2: persistent mega-conv, 256 blocks (1/CU), perfectly packed
    mega_conv<<<256, 512, 0, stream>>>(
        sin_, kin, wst, wkt,
        bsg, bsb, bsm, bsv, bkg, bkb, bkm, bkv,
        sbuf, kbuf);

    // L3: depthwise xcorr
    xcorr_dw<<<128 * (C / 2), 256, 0, stream>>>(sbuf, kbuf, out);
}

// Round 16
// 222.571 us; speedup vs baseline: 1.0219x; 1.0219x over previous
//
#include <hip/hip_runtime.h>
#include <hip/hip_bf16.h>

#define BN_EPS 1e-5f
constexpr int C = 256;

typedef __attribute__((ext_vector_type(8))) short bf16x8;
typedef __attribute__((ext_vector_type(4))) float f32x4;
typedef __attribute__((ext_vector_type(2))) unsigned int u32x2;

static __device__ __forceinline__ unsigned short f2bf(float f) {
    __hip_bfloat16 h = __float2bfloat16(f);
    return *reinterpret_cast<unsigned short*>(&h);
}
static __device__ __forceinline__ float bf2f(unsigned short u) {
    unsigned int v = ((unsigned int)u) << 16;
    return __uint_as_float(v);
}
static __device__ __forceinline__ unsigned int pack_bf2(float a, float b) {
    return (unsigned int)f2bf(a) | ((unsigned int)f2bf(b) << 16);
}

// ---------------------------------------------------------------------------
// WPREP: fold BN scale into weights, transpose [N][C][9] f32 -> [9][N][C] bf16.
// ---------------------------------------------------------------------------
__global__ __launch_bounds__(256) void wprep_both(
    const float* __restrict__ wk, const float* __restrict__ bkg, const float* __restrict__ bkv,
    unsigned short* __restrict__ wkt,
    const float* __restrict__ ws, const float* __restrict__ bsg, const float* __restrict__ bsv,
    unsigned short* __restrict__ wst)
{
    const int bid = blockIdx.x, t = threadIdx.x;
    const bool isk = bid < 256;
    const int n = isk ? bid : bid - 256;
    const float* w = isk ? wk : ws;
    const float* g = isk ? bkg : bsg;
    const float* v = isk ? bkv : bsv;
    unsigned short* wt = isk ? wkt : wst;
    const float scale = g[n] * rsqrtf(v[n] + BN_EPS);
    const float* wp = w + ((size_t)n * C + t) * 9;
#pragma unroll
    for (int k = 0; k < 9; ++k)
        wt[((size_t)k * C + n) * C + t] = f2bf(wp[k] * scale);
}

// ---------------------------------------------------------------------------
// MEGA (r14 structure): blocks [0,512) = search conv, [512,640) = kernel conv.
// Transpose-free A staging from fp32 NCHW. A-staging writes are b64 at 2-way
// bank aliasing (wave w owns channels 4w..4w+3 of each 32-ch chunk).
// ---------------------------------------------------------------------------
__global__ __launch_bounds__(512, 2) void mega_conv(
    const float* __restrict__ sin_,          // [128][256][961] fp32
    const float* __restrict__ kin,           // [128][256][49]  fp32
    const unsigned short* __restrict__ wst,  // [9][256][256] bf16
    const unsigned short* __restrict__ wkt,  // [9][256][256] bf16
    const float* __restrict__ bsg, const float* __restrict__ bsb,
    const float* __restrict__ bsm, const float* __restrict__ bsv,
    const float* __restrict__ bkg, const float* __restrict__ bkb,
    const float* __restrict__ bkm, const float* __restrict__ bkv,
    unsigned short* __restrict__ sbuf,       // [128][256][844] bf16
    float* __restrict__ kbuf)                // [128][256][28]  f32
{
    constexpr int WOUT = 29, NPOS = 841;
    constexpr int BM = 224, MF = 7, NF = 4;
    constexpr int LDK = 36;
    constexpr int ROWS = 11;
    constexpr int APIX = ROWS * 31;          // 341
    constexpr int ABUF = APIX * LDK;         // 12276 shorts
    constexpr int BBUF = 256 * LDK;          // 9216 shorts
    constexpr int BIT = 2;

    __shared__ __align__(16) short s_a[2 * ABUF];   // 49,104 B
    __shared__ __align__(16) short s_b[4 * BBUF];   // 73,728 B

    const int bid = blockIdx.x;
    const int t = threadIdx.x;
    const int lane = t & 63, wave = t >> 6;
    const int lr = lane >> 4, lc = lane & 15;

    if (bid >= 512) {
        // ================= KERNEL CONV role =================
        constexpr int KW = 7, KHW = 49, KWOUT = 5, KNPOS = 25;
        constexpr int KMF = 2, KNF = 2;
        const int kb = bid - 512;            // 0..127
        const int n0 = (kb & 1) * 128;
        const int b0 = (kb >> 1) * 2;
        const int wm = wave >> 2, wn = wave & 3;

        short* ka = s_a;                      // [2*49][36] shorts

        int arow[KMF];
#pragma unroll
        for (int m = 0; m < KMF; ++m) {
            int p = m * 16 + lc;
            p = p < KNPOS ? p : KNPOS - 1;
            int y = p / KWOUT, x = p - y * KWOUT;
            arow[m] = ((wm * KHW) + y * KW + x) * LDK + lr * 8;
        }

        f32x4 acc[KMF][KNF];
#pragma unroll
        for (int m = 0; m < KMF; ++m)
#pragma unroll
            for (int n = 0; n < KNF; ++n) acc[m][n] = f32x4{0.f, 0.f, 0.f, 0.f};

        const bool kval = lane < KHW;
        int sbb[4], scq[4];
#pragma unroll
        for (int j = 0; j < 4; ++j) {
            int idx = wave * 4 + j;
            sbb[j] = idx >> 4; scq[j] = (idx & 15) * 2;
        }
        const float* kbase = kin + (size_t)b0 * C * KHW + lane;

        float k0s[4], k1s[4];
#define KA_LOAD(c0_)                                                           \
        _Pragma("unroll")                                                      \
        for (int j = 0; j < 4; ++j) {                                          \
            if (kval) {                                                        \
                const float* p_ = kbase + ((size_t)sbb[j] * C + (c0_) + scq[j]) * KHW; \
                k0s[j] = p_[0]; k1s[j] = p_[KHW];                              \
            }                                                                  \
        }
#define KA_WRITE()                                                             \
        _Pragma("unroll")                                                      \
        for (int j = 0; j < 4; ++j) {                                          \
            if (kval)                                                          \
                *(unsigned int*)&ka[(sbb[j] * KHW + lane) * LDK + scq[j]] =    \
                    pack_bf2(k0s[j], k1s[j]);                                  \
        }

        const unsigned short* wb = wkt + (size_t)(n0 + wn * 32 + lc) * C + lr * 8;

        KA_LOAD(0)
        KA_WRITE()

#pragma unroll 1
        for (int ch = 0; ch < 8; ++ch) {
            const int c0 = ch * 32;
            __syncthreads();

            if (ch < 7) { KA_LOAD(c0 + 32) }

            bf16x8 bcur[KNF], bnxt[KNF];
#pragma unroll
            for (int n = 0; n < KNF; ++n)
                bnxt[n] = *(const bf16x8*)&wb[(size_t)0 + n * (16 * C) + c0];

#pragma unroll
            for (int tap = 0; tap < 9; ++tap) {
                const int dy = tap / 3, dx = tap % 3;
#pragma unroll
                for (int n = 0; n < KNF; ++n) bcur[n] = bnxt[n];
                if (tap < 8) {
#pragma unroll
                    for (int n = 0; n < KNF; ++n)
                        bnxt[n] = *(const bf16x8*)&wb[(size_t)(tap + 1) * (C * C) + n * (16 * C) + c0];
                }
                bf16x8 af[KMF];
#pragma unroll
                for (int m = 0; m < KMF; ++m)
                    af[m] = *(const bf16x8*)&ka[arow[m] + (dy * KW + dx) * LDK];
#pragma unroll
                for (int m = 0; m < KMF; ++m)
#pragma unroll
                    for (int n = 0; n < KNF; ++n)
                        acc[m][n] = __builtin_amdgcn_mfma_f32_16x16x32_bf16(
                            af[m], bcur[n], acc[m][n], 0, 0, 0);
            }

            __syncthreads();
            if (ch < 7) { KA_WRITE() }
        }
#undef KA_LOAD
#undef KA_WRITE

#pragma unroll
        for (int n = 0; n < KNF; ++n) {
            const int co = n0 + wn * 32 + n * 16 + lc;
            const float sc = bkg[co] * rsqrtf(bkv[co] + BN_EPS);
            const float bias = bkb[co] - bkm[co] * sc;
#pragma unroll
            for (int m = 0; m < KMF; ++m) {
                int p = m * 16 + lr * 4;
                int b = b0 + wm;
                f32x4 v = acc[m][n];
                float rr[4] = {fmaxf(v.x + bias, 0.f), fmaxf(v.y + bias, 0.f),
                               fmaxf(v.z + bias, 0.f), fmaxf(v.w + bias, 0.f)};
                float* op = kbuf + ((size_t)b * C + co) * 28 + p;
#pragma unroll
                for (int i = 0; i < 4; ++i)
                    if (p + i < KNPOS) op[i] = rr[i];
            }
        }
        return;
    }

    // ================= SEARCH CONV role =================
    const int wm = wave >> 2, wn = wave & 3;
    const int p0 = (bid & 3) * BM;
    const int b  = bid >> 2;
    const int y0 = p0 / WOUT;
    const int R  = min(ROWS, 31 - y0);
    const int npix = R * 31;

    int arow[MF];
#pragma unroll
    for (int m = 0; m < MF; ++m) {
        int pm = wm * 112 + m * 16 + lc;
        int p = p0 + pm; p = p < NPOS ? p : NPOS - 1;
        int y = p / WOUT, x = p - y * WOUT;
        arow[m] = ((y - y0) * 31 + x) * LDK + lr * 8;
    }

    // A staging: fp32 NCHW direct. Wave w owns channels 4w..4w+3 of each
    // 32-ch chunk; per seg one b64 write (2-way bank alias = free).
    const float* abase = sin_ + (size_t)b * C * 961 + y0 * 31 + lane;
    const int wch = 4 * wave;                // channel offset in chunk
    bool segv[6];
#pragma unroll
    for (int seg = 0; seg < 6; ++seg) segv[seg] = (seg * 64 + lane) < npix;

    float as0[6], as1[6], as2[6], as3[6];
#define SA_LOAD(c0_)                                                           \
    {                                                                          \
        const size_t cb0_ = (size_t)((c0_) + wch) * 961;                       \
        _Pragma("unroll")                                                      \
        for (int seg = 0; seg < 6; ++seg) {                                    \
            if (segv[seg]) {                                                   \
                as0[seg] = abase[cb0_ + seg * 64];                             \
                as1[seg] = abase[cb0_ + 961 + seg * 64];                       \
                as2[seg] = abase[cb0_ + 2 * 961 + seg * 64];                   \
                as3[seg] = abase[cb0_ + 3 * 961 + seg * 64];                   \
            }                                                                  \
        }                                                                      \
    }
#define SA_WRITE(dst_)                                                         \
    _Pragma("unroll")                                                          \
    for (int seg = 0; seg < 6; ++seg) {                                        \
        if (segv[seg]) {                                                       \
            u32x2 v_;                                                          \
            v_.x = pack_bf2(as0[seg], as1[seg]);                               \
            v_.y = pack_bf2(as2[seg], as3[seg]);                               \
            *(u32x2*)&s_a[(dst_) + (seg * 64 + lane) * LDK + wch] = v_;        \
        }                                                                      \
    }

    // B staging decomposition
    const unsigned short* bptr[BIT]; int boff[BIT];
#pragma unroll
    for (int it = 0; it < BIT; ++it) {
        int i = t + it * 512;
        int n = i >> 2, sl = i & 3;
        bptr[it] = wst + (size_t)n * 256 + sl * 8;
        boff[it] = n * LDK + sl * 8;
    }

    f32x4 acc[MF][NF];
#pragma unroll
    for (int m = 0; m < MF; ++m)
#pragma unroll
        for (int n = 0; n < NF; ++n) acc[m][n] = f32x4{0.f, 0.f, 0.f, 0.f};

    bf16x8 bstg0[BIT], bstg1[BIT];

    // prologue: A chunk 0; B steps 0,1
    SA_LOAD(0)
#pragma unroll
    for (int it = 0; it < BIT; ++it) bstg0[it] = *(const bf16x8*)(bptr[it]);
#pragma unroll
    for (int it = 0; it < BIT; ++it) bstg1[it] = *(const bf16x8*)(bptr[it] + 65536);
    SA_WRITE(0)
#pragma unroll
    for (int it = 0; it < BIT; ++it) *(bf16x8*)&s_b[boff[it]] = bstg0[it];
#pragma unroll
    for (int it = 0; it < BIT; ++it) *(bf16x8*)&s_b[BBUF + boff[it]] = bstg1[it];
    __syncthreads();

#define READ_FRAGS(S, AF, BF)                                                  \
    {                                                                          \
        const int tap_ = (S) % 9;                                              \
        const int dt_ = (tap_ / 3) * 31 + (tap_ % 3);                          \
        const int ab_ = (((S) / 9) & 1) * ABUF;                                \
        const int bb_ = ((S) & 3) * BBUF;                                      \
        _Pragma("unroll")                                                      \
        for (int n = 0; n < NF; ++n)                                           \
            BF[n] = *(const bf16x8*)&s_b[bb_ + (wn * 64 + n * 16 + lc) * LDK + lr * 8]; \
        _Pragma("unroll")                                                      \
        for (int m = 0; m < MF; ++m)                                           \
            AF[m] = *(const bf16x8*)&s_a[ab_ + arow[m] + dt_ * LDK];           \
    }

#define MFMA_STEP(AF, BF)                                                      \
    _Pragma("unroll")                                                          \
    for (int m = 0; m < MF; ++m)                                               \
        _Pragma("unroll")                                                      \
        for (int n = 0; n < NF; ++n)                                           \
            acc[m][n] = __builtin_amdgcn_mfma_f32_16x16x32_bf16(               \
                AF[m], BF[n], acc[m][n], 0, 0, 0);

#pragma unroll 1
    for (int pr = 0; pr < 35; ++pr) {
        const int s0 = 2 * pr, s1 = s0 + 1;

        // A issue at chunk-start pair
        {
            const int cb = (s0 % 9 == 0) ? s0 / 9 : ((s1 % 9 == 0) ? s1 / 9 : -1);
            if (cb >= 0 && cb < 7) {
                const int cn = (cb + 1) * 32;
                SA_LOAD(cn)
            }
        }

        bf16x8 af0[MF], bf0[NF], af1[MF], bf1[NF];
        READ_FRAGS(s0, af0, bf0)
        READ_FRAGS(s1, af1, bf1)

        MFMA_STEP(af0, bf0)

        // mid-pair B global issues for steps s0+2, s1+2
        {
            const int u0 = s0 + 2, u1 = s1 + 2;
            const int t0 = u0 % 9, c0_ = (u0 / 9) * 32;
            const int t1 = u1 % 9, c1_ = (u1 / 9) * 32;
#pragma unroll
            for (int it = 0; it < BIT; ++it)
                bstg0[it] = *(const bf16x8*)(bptr[it] + (size_t)t0 * 65536 + c0_);
#pragma unroll
            for (int it = 0; it < BIT; ++it)
                bstg1[it] = *(const bf16x8*)(bptr[it] + (size_t)t1 * 65536 + c1_);
        }

        MFMA_STEP(af1, bf1)

        // B pair-end writes
        {
            const int w0 = ((s0 + 2) & 3) * BBUF, w1 = ((s1 + 2) & 3) * BBUF;
#pragma unroll
            for (int it = 0; it < BIT; ++it)
                *(bf16x8*)&s_b[w0 + boff[it]] = bstg0[it];
#pragma unroll
            for (int it = 0; it < BIT; ++it)
                *(bf16x8*)&s_b[w1 + boff[it]] = bstg1[it];
        }

        // A write at chunk-end pair
        {
            const int cw = (s0 % 9 == 7) ? s0 / 9 : ((s1 % 9 == 7) ? s1 / 9 : -1);
            if (cw >= 0 && cw < 7) {
                const int dst = ((cw & 1) ^ 1) * ABUF;
                SA_WRITE(dst)
            }
        }
        __syncthreads();
    }

    // final pair: s = 70, 71
    {
        bf16x8 af0[MF], bf0[NF], af1[MF], bf1[NF];
        READ_FRAGS(70, af0, bf0)
        READ_FRAGS(71, af1, bf1)
        MFMA_STEP(af0, bf0)
        MFMA_STEP(af1, bf1)
    }
#undef READ_FRAGS
#undef MFMA_STEP
#undef SA_LOAD
#undef SA_WRITE

    // epilogue: bias + relu -> bf16 planes (padded stride 844)
#pragma unroll
    for (int n = 0; n < NF; ++n) {
        const int co = wn * 64 + n * 16 + lc;
        const float sc = bsg[co] * rsqrtf(bsv[co] + BN_EPS);
        const float bias = bsb[co] - bsm[co] * sc;
#pragma unroll
        for (int m = 0; m < MF; ++m) {
            int pm = wm * 112 + m * 16 + lr * 4;
            int p = p0 + pm;
            f32x4 v = acc[m][n];
            float r0 = fmaxf(v.x + bias, 0.f);
            float r1 = fmaxf(v.y + bias, 0.f);
            float r2 = fmaxf(v.z + bias, 0.f);
            float r3 = fmaxf(v.w + bias, 0.f);
            unsigned short* op = sbuf + ((size_t)b * C + co) * 844 + p;
            if (p + 4 <= NPOS) {
                ushort4 pk;
                pk.x = f2bf(r0); pk.y = f2bf(r1); pk.z = f2bf(r2); pk.w = f2bf(r3);
                *(ushort4*)op = pk;
            } else {
                float rr[4] = {r0, r1, r2, r3};
#pragma unroll
                for (int i = 0; i < 4; ++i)
                    if (p + i < NPOS) op[i] = f2bf(rr[i]);
            }
        }
    }
}

// ---------------------------------------------------------------------------
// Depthwise 5x5 valid xcorr: 2 channels/block, 5 outputs/thread (5x9 window).
// ---------------------------------------------------------------------------
__global__ __launch_bounds__(256) void xcorr_dw(
    const unsigned short* __restrict__ s, const float* __restrict__ k,
    float* __restrict__ out)
{
    const int bc0 = blockIdx.x * 2;
    const int t = threadIdx.x;

    __shared__ float s_s[2][844];
    __shared__ float s_k[2][25];

#pragma unroll
    for (int it = 0; it < 2; ++it) {
        int i = t + it * 256;
        if (i < 422) {
            int pl = i < 211 ? 0 : 1;
            int q = i - pl * 211;
            ushort4 v = *(const ushort4*)(s + (size_t)(bc0 + pl) * 844 + 4 * q);
            s_s[pl][4 * q + 0] = bf2f(v.x);
            s_s[pl][4 * q + 1] = bf2f(v.y);
            s_s[pl][4 * q + 2] = bf2f(v.z);
            s_s[pl][4 * q + 3] = bf2f(v.w);
        }
    }
    if (t < 50) s_k[t / 25][t % 25] = k[(size_t)(bc0 + t / 25) * 28 + t % 25];
    __syncthreads();

    if (t >= 250) return;
    const int ch = t / 125;
    const int r = t - ch * 125;
    const int y = r / 5;
    const int xb = (r - y * 5) * 5;

    float kk[25];
#pragma unroll
    for (int i = 0; i < 25; ++i) kk[i] = s_k[ch][i];

    float w[5][9];
#pragma unroll
    for (int dy = 0; dy < 5; ++dy)
#pragma unroll
        for (int dx = 0; dx < 9; ++dx)
            w[dy][dx] = s_s[ch][(y + dy) * 29 + xb + dx];

    float o[5] = {0.f, 0.f, 0.f, 0.f, 0.f};
#pragma unroll
    for (int dy = 0; dy < 5; ++dy)
#pragma unroll
        for (int dx = 0; dx < 5; ++dx) {
            const float kv = kk[dy * 5 + dx];
#pragma unroll
            for (int oo = 0; oo < 5; ++oo)
                o[oo] += w[dy][oo + dx] * kv;
        }

    float* op = out + (size_t)(bc0 + ch) * 625 + y * 25 + xb;
#pragma unroll
    for (int oo = 0; oo < 5; ++oo) op[oo] = o[oo];
}

extern "C" void kernel_launch(void* const* d_in, const int* in_sizes, int n_in,
                              void* d_out, int out_size, void* d_ws, size_t ws_size,
                              hipStream_t stream) {
    const float* kin = (const float*)d_in[0];   // [128,256,7,7]
    const float* sin_ = (const float*)d_in[1];  // [128,256,31,31]
    const float* wk = (const float*)d_in[2];
    const float* bkg = (const float*)d_in[3];
    const float* bkb = (const float*)d_in[4];
    const float* bkm = (const float*)d_in[5];
    const float* bkv = (const float*)d_in[6];
    const float* ws_ = (const float*)d_in[7];
    const float* bsg = (const float*)d_in[8];
    const float* bsb = (const float*)d_in[9];
    const float* bsm = (const float*)d_in[10];
    const float* bsv = (const float*)d_in[11];
    float* out = (float*)d_out;

    // workspace: wkt | wst | sbuf bf16 [128][256][844] | kbuf f32 [128][256][28]
    char* base = (char*)d_ws;
    unsigned short* wkt = (unsigned short*)base;               // 1,179,648 B
    unsigned short* wst = wkt + (size_t)9 * C * C;             // 1,179,648 B
    unsigned short* sbuf = (unsigned short*)(base + 2359296);  // 55,312,384 B
    float* kbuf = (float*)(base + 2359296 + 55312384);         //  3,670,016 B

    // L1: weight prep (both convs)
    wprep_both<<<512, 256, 0, stream>>>(wk, bkg, bkv, wkt, ws_, bsg, bsv, wst);

    // L2: search conv (512 blocks) + kernel conv (128 blocks), transpose-free
    mega_conv<<<640, 512, 0, stream>>>(
        sin_, kin, wst, wkt,
        bsg, bsb, bsm, bsv, bkg, bkb, bkm, bkv,
        sbuf, kbuf);

    // L3: depthwise xcorr
    xcorr_dw<<<128 * (C / 2), 256, 0, stream>>>(sbuf, kbuf, out);
}